// Round 14
// baseline (386.640 us; speedup 1.0000x reference)
//
#include <hip/hip_runtime.h>
#include <math.h>

// Problem constants
constexpr int kB = 4, kG = 2048, kD = 256, kH = 8, kHD = 32, kL = 4, kFFN = 1024;
constexpr int kBG = kB * kG;                  // 8192 tokens
constexpr int kCHUNK = 64;                    // linear-attn chunk length
constexpr int kNC = kG / kCHUNK;              // 32 chunks per sequence
constexpr int kSUMSZ = kHD * kHD + kHD;       // 1056 floats per chunk-state
constexpr int kQKVN = 3 * kD;                 // 768 fused QKV columns

typedef __bf16 bf16x8 __attribute__((ext_vector_type(8)));
typedef unsigned short ushort8 __attribute__((ext_vector_type(8)));
typedef float floatx4 __attribute__((ext_vector_type(4)));

__device__ __forceinline__ unsigned short f2bf(float f) {
  unsigned int u = __float_as_uint(f);
  u += 0x7fff + ((u >> 16) & 1);              // round-to-nearest-even
  return (unsigned short)(u >> 16);
}
__device__ __forceinline__ float bf2f(unsigned short u) {
  return __uint_as_float(((unsigned int)u) << 16);
}

__device__ __forceinline__ void load_lds_16(const void* g, void* l) {
  __builtin_amdgcn_global_load_lds((const __attribute__((address_space(1))) void*)g,
                                   (__attribute__((address_space(3))) void*)l,
                                   16, 0, 0);
}

// ---------------------------------------------------------------------------
// h[b,g,d] = gene_emb[g,d] + ree(x[b,g], d)
__global__ void embed_kernel(const float* __restrict__ x,
                             const float* __restrict__ ge,
                             float* __restrict__ h) {
  int idx = blockIdx.x * 256 + threadIdx.x;   // over kB*kG*kD = 2^21
  int d = idx & (kD - 1);
  int g = (idx >> 8) & (kG - 1);
  int b = idx >> 19;
  float xv = x[b * kG + g];
  int i = d & 127;
  float inv = expf(-(float)i * (4.6051701859880914f / 128.0f));  // 100^(-i/128)
  float f = xv * inv;
  float r = (d < 128) ? sinf(f) : cosf(f);
  if (xv == -10.0f) r = 0.0f;
  h[idx] = ge[g * kD + d] + r;
}

// ---------------------------------------------------------------------------
// Weight conversion: fp32 K-major -> bf16 N-major (transposed), plus QKV bias
// packing. One launch covers all layers.
__global__ void convert_weights_kernel(
    const float* __restrict__ Wq, const float* __restrict__ Wk,
    const float* __restrict__ Wv, const float* __restrict__ WU,
    const float* __restrict__ WV, const float* __restrict__ bq,
    const float* __restrict__ bk, const float* __restrict__ bv,
    unsigned short* __restrict__ Wqkv_t, unsigned short* __restrict__ WU_t,
    unsigned short* __restrict__ WV_t, float* __restrict__ bias_qkv) {
  int blk = blockIdx.x;
  if (blk >= kL * 704) {                       // bias-packing tail blocks
    int idx = (blk - kL * 704) * 256 + threadIdx.x;
    if (idx < kL * kQKVN) {
      int l = idx / kQKVN, n = idx % kQKVN;
      float v = (n < 256) ? bq[l * 256 + n]
              : (n < 512) ? bk[l * 256 + n - 256]
                          : bv[l * 256 + n - 512];
      bias_qkv[idx] = v;
    }
    return;
  }
  int l = blk / 704, id = blk % 704;
  const float* src;
  unsigned short* dst;
  int Ksrc, Nsrc, kt, nt;
  if (id < 192) {
    int m = id >> 6, tid = id & 63;
    src = (m == 0 ? Wq : m == 1 ? Wk : Wv) + (size_t)l * 256 * 256;
    dst = Wqkv_t + (size_t)l * kQKVN * 256 + (size_t)m * 256 * 256;
    Ksrc = 256; Nsrc = 256; kt = tid >> 3; nt = tid & 7;
  } else if (id < 448) {
    int tid = id - 192;
    src = WU + (size_t)l * 256 * 1024;
    dst = WU_t + (size_t)l * 1024 * 256;
    Ksrc = 256; Nsrc = 1024; kt = tid >> 5; nt = tid & 31;
  } else {
    int tid = id - 448;
    src = WV + (size_t)l * 1024 * 256;
    dst = WV_t + (size_t)l * 256 * 1024;
    Ksrc = 1024; Nsrc = 256; kt = tid >> 3; nt = tid & 7;
  }
  __shared__ float s[32][33];
  int tx = threadIdx.x & 31, ty = threadIdx.x >> 5;   // 32 x 8
#pragma unroll
  for (int r = 0; r < 4; r++)
    s[ty + r * 8][tx] = src[(size_t)(kt * 32 + ty + r * 8) * Nsrc + nt * 32 + tx];
  __syncthreads();
#pragma unroll
  for (int r = 0; r < 4; r++)
    dst[(size_t)(nt * 32 + ty + r * 8) * Ksrc + kt * 32 + tx] =
        f2bf(s[tx][ty + r * 8]);
}

// ---------------------------------------------------------------------------
// Row LayerNorm over D=256 -> bf16 output. Wave-per-row, 4 rows/block.
__global__ __launch_bounds__(256) void ln_kernel(
    const float* __restrict__ h, const float* __restrict__ gamma,
    const float* __restrict__ beta, unsigned short* __restrict__ z) {
  int w = threadIdx.x >> 6, lane = threadIdx.x & 63;
  size_t row = (size_t)blockIdx.x * 4 + w;
  float4 v = *(const float4*)&h[row * kD + lane * 4];
  float s = v.x + v.y + v.z + v.w;
  float sq = v.x * v.x + v.y * v.y + v.z * v.z + v.w * v.w;
#pragma unroll
  for (int o = 32; o > 0; o >>= 1) {
    s += __shfl_xor(s, o);
    sq += __shfl_xor(sq, o);
  }
  float mu = s * (1.0f / kD);
  float var = sq * (1.0f / kD) - mu * mu;
  float r = rsqrtf(var + 1e-5f);
  float4 g4 = *(const float4*)&gamma[lane * 4];
  float4 b4 = *(const float4*)&beta[lane * 4];
  float y0 = (v.x - mu) * r * g4.x + b4.x;
  float y1 = (v.y - mu) * r * g4.y + b4.y;
  float y2 = (v.z - mu) * r * g4.z + b4.z;
  float y3 = (v.w - mu) * r * g4.w + b4.w;
  unsigned int u0 = (unsigned int)f2bf(y0) | ((unsigned int)f2bf(y1) << 16);
  unsigned int u1 = (unsigned int)f2bf(y2) | ((unsigned int)f2bf(y3) << 16);
  uint2 uu; uu.x = u0; uu.y = u1;
  *(uint2*)&z[row * kD + lane * 4] = uu;
}

// ---------------------------------------------------------------------------
// bf16 MFMA GEMM, 64x64 tile, BK=64 double-buffered (round-11 shape,
// runtime K — r13 showed full unroll of long K-loops regresses).
// A: M x K bf16 (row-major), Bt: N x K bf16 (row-major = W transposed).
// kOff/kLen: K-range this block covers (split-K support; kOff=0,kLen=K normally).
// EPI: 1 = fused QKV: cols<512 -> square -> bf16 into Cout [M][512];
//                     cols>=512 -> fp32 into Cout2 [M][256]
//      2 = exact gelu, bf16 out
//      3 = split-K residual accumulate: atomicAdd into fp32 Cout (which
//          already holds the residual); bias added by the blockIdx.z==0 split.
template <int EPI>
__global__ __launch_bounds__(256) void mfma_gemm(
    const unsigned short* __restrict__ A, const unsigned short* __restrict__ Bt,
    const float* __restrict__ bias, void* __restrict__ Cout,
    void* __restrict__ Cout2, int M, int N, int K, int kLen) {
  __shared__ unsigned short As[2][2][64 * 32];   // [buf][kc] = 16 KB
  __shared__ unsigned short Bs[2][2][64 * 32];   // 16 KB
  const int t = threadIdx.x;
  const int w = t >> 6, lane = t & 63;
  const int bm = blockIdx.y * 64, bn = blockIdx.x * 64;
  const int kOff = blockIdx.z * kLen;
  const int wm = (w >> 1) * 32, wn = (w & 1) * 32;

  const int srow = lane >> 2;            // 0..15 within chunk
  const int skof = (lane & 3) * 8;       // k element offset of 16B piece
  const unsigned short* ap = A + (size_t)(bm + w * 16 + srow) * K + kOff + skof;
  const unsigned short* bp = Bt + (size_t)(bn + w * 16 + srow) * K + kOff + skof;

  floatx4 acc[2][2];
#pragma unroll
  for (int i = 0; i < 2; i++)
#pragma unroll
    for (int j = 0; j < 2; j++) acc[i][j] = (floatx4){0.f, 0.f, 0.f, 0.f};

  const int lm = lane & 15, lq = lane >> 4;
  const int nsteps = kLen >> 6;          // kLen is a multiple of 64

  // Prologue: stage step 0 (two 32-deep chunks) into buffer 0.
  load_lds_16(ap, &As[0][0][w * 512]);
  load_lds_16(ap + 32, &As[0][1][w * 512]);
  load_lds_16(bp, &Bs[0][0][w * 512]);
  load_lds_16(bp + 32, &Bs[0][1][w * 512]);
  __syncthreads();

  for (int s = 0; s < nsteps; s++) {
    const int cur = s & 1, nxt = cur ^ 1;
    if (s + 1 < nsteps) {                     // prefetch next 64-deep step
      const int k1 = (s + 1) * 64;
      load_lds_16(ap + k1, &As[nxt][0][w * 512]);
      load_lds_16(ap + k1 + 32, &As[nxt][1][w * 512]);
      load_lds_16(bp + k1, &Bs[nxt][0][w * 512]);
      load_lds_16(bp + k1 + 32, &Bs[nxt][1][w * 512]);
    }
#pragma unroll
    for (int kc = 0; kc < 2; kc++) {
      const unsigned short* afp = &As[cur][kc][(wm + lm) * 32 + lq * 8];
      const unsigned short* bfp = &Bs[cur][kc][(wn + lm) * 32 + lq * 8];
      bf16x8 af[2], bfr[2];
#pragma unroll
      for (int i = 0; i < 2; i++)
        af[i] = __builtin_bit_cast(bf16x8,
            *reinterpret_cast<const ushort8*>(afp + i * 16 * 32));
#pragma unroll
      for (int j = 0; j < 2; j++)
        bfr[j] = __builtin_bit_cast(bf16x8,
            *reinterpret_cast<const ushort8*>(bfp + j * 16 * 32));
#pragma unroll
      for (int i = 0; i < 2; i++)
#pragma unroll
        for (int j = 0; j < 2; j++)
          acc[i][j] = __builtin_amdgcn_mfma_f32_16x16x32_bf16(af[i], bfr[j],
                                                              acc[i][j], 0, 0, 0);
    }
    __syncthreads();
  }

  const int r0 = bm + wm + lq * 4;
  const int c0 = bn + wn + lm;
#pragma unroll
  for (int j = 0; j < 2; j++) {
    int col = c0 + j * 16;
    float bv = (EPI == 3 && blockIdx.z != 0) ? 0.f : bias[col];
#pragma unroll
    for (int i = 0; i < 2; i++) {
      int rowb = r0 + i * 16;
#pragma unroll
      for (int r = 0; r < 4; r++) {
        int row = rowb + r;
        float v = acc[i][j][r] + bv;
        if (EPI == 1) {
          if (col < 512) {                    // q,k: squared, bf16
            ((unsigned short*)Cout)[(size_t)row * 512 + col] = f2bf(v * v);
          } else {                            // v: fp32
            ((float*)Cout2)[(size_t)row * 256 + col - 512] = v;
          }
        } else if (EPI == 2) {
          float g = 0.5f * v * (1.0f + erff(v * 0.70710678118654752f));
          ((unsigned short*)Cout)[(size_t)row * N + col] = f2bf(g);
        } else {
          // split-K: Cout (h) already holds the residual; accumulate.
          atomicAdd(&((float*)Cout)[(size_t)row * N + col], v);
        }
      }
    }
  }
}

// ---------------------------------------------------------------------------
// Per-chunk summaries via MFMA: Skv = k̃ᵀ·ṽ (K=64). k,v staged transposed;
// 4 waves x one 16x16 tile x 2 MFMAs. ksum fp32 from kT rows. (round-11)
__global__ __launch_bounds__(256) void attn_sums_kernel(
    const unsigned short* __restrict__ qkb, const float* __restrict__ vbuf,
    float* __restrict__ sums) {
  int blk = blockIdx.x;              // b*(H*NC) + h*NC + c
  int c = blk & (kNC - 1);
  int hh = (blk >> 5) & (kH - 1);
  int b = blk >> 8;
  int g0 = c * kCHUNK;
  constexpr int TST = 72;                    // transposed row stride (bf16)
  __shared__ unsigned short kT[kHD * TST];   // [m][g] 4.5 KB
  __shared__ unsigned short vT[kHD * TST];   // [n][g] 4.5 KB
  int t = threadIdx.x;
  // k (bf16, already squared): transpose into kT
  {
    int i = t >> 2, j8 = (t & 3) * 8;        // row g0+i, k-feature cols j8..+7
    ushort8 kv = *(const ushort8*)&qkb[(size_t)(b * kG + g0 + i) * 512 + 256 +
                                       hh * kHD + j8];
#pragma unroll
    for (int e = 0; e < 8; e++) kT[(j8 + e) * TST + i] = kv[e];
  }
  // v (fp32): bf16 transpose into vT
#pragma unroll
  for (int r = 0; r < 2; r++) {
    int e = t + r * 256;
    int j = e >> 3, n0 = (e & 7) * 4;
    float4 vv = *(const float4*)&vbuf[(size_t)(b * kG + g0 + j) * kD + hh * kHD + n0];
    vT[(n0 + 0) * TST + j] = f2bf(vv.x);
    vT[(n0 + 1) * TST + j] = f2bf(vv.y);
    vT[(n0 + 2) * TST + j] = f2bf(vv.z);
    vT[(n0 + 3) * TST + j] = f2bf(vv.w);
  }
  __syncthreads();
  float* outp = sums + (size_t)blk * kSUMSZ;
  const int w = t >> 6, lane = t & 63;
  const int lm = lane & 15, lq = lane >> 4;
  const int m0 = (w >> 1) * 16, n0 = (w & 1) * 16;
  floatx4 acc = (floatx4){0.f, 0.f, 0.f, 0.f};
#pragma unroll
  for (int kc = 0; kc < 2; kc++) {
    bf16x8 af = __builtin_bit_cast(bf16x8,
        *reinterpret_cast<const ushort8*>(&kT[(m0 + lm) * TST + kc * 32 + lq * 8]));
    bf16x8 bf = __builtin_bit_cast(bf16x8,
        *reinterpret_cast<const ushort8*>(&vT[(n0 + lm) * TST + kc * 32 + lq * 8]));
    acc = __builtin_amdgcn_mfma_f32_16x16x32_bf16(af, bf, acc, 0, 0, 0);
  }
  // C-layout: row (m) = m0 + lq*4 + r, col (n) = n0 + lm
#pragma unroll
  for (int r = 0; r < 4; r++)
    outp[(m0 + lq * 4 + r) * kHD + n0 + lm] = acc[r];
  // ksum[m] = sum_g k[g][m] — fp32 accumulate from kT row m
  if (t < kHD) {
    float s = 0;
#pragma unroll
    for (int g = 0; g < kCHUNK; g++) s += bf2f(kT[t * TST + g]);
    outp[kHD * kHD + t] = s;
  }
}

// ---------------------------------------------------------------------------
// Exclusive prefix scan over chunks. grid = kB*kH*5, block = 256.
// (Separate launch on purpose: in-kernel fusion needs per-block device-scope
// fences, which cost a per-block L2 writeback on multi-XCD CDNA — r12.)
__global__ void attn_scan_kernel(float* __restrict__ sums) {
  int bh = blockIdx.x / 5, part = blockIdx.x % 5;
  int e = part * 256 + threadIdx.x;
  if (e >= kSUMSZ) return;
  float* base = sums + (size_t)bh * kNC * kSUMSZ + e;
  float v[kNC];
#pragma unroll
  for (int c = 0; c < kNC; c++) v[c] = base[(size_t)c * kSUMSZ];
  float run = 0;
#pragma unroll
  for (int c = 0; c < kNC; c++) {
    float tv = v[c];
    base[(size_t)c * kSUMSZ] = run;
    run += tv;
  }
}

// ---------------------------------------------------------------------------
// Per-chunk output, both stages on MFMA (round-9 structure).
__global__ __launch_bounds__(256) void attn_out_kernel(
    const unsigned short* __restrict__ qkb, const float* __restrict__ vbuf,
    const float* __restrict__ sums, float* __restrict__ h) {
  int blk = blockIdx.x;
  int c = blk & (kNC - 1);
  int hh = (blk >> 5) & (kH - 1);
  int b = blk >> 8;
  int g0 = c * kCHUNK;
  constexpr int PST = 104;                    // row stride (bf16 elems)
  __shared__ unsigned short Pq[kCHUNK * PST]; // 13 KB: [64][104]
  __shared__ unsigned short kb[kCHUNK * 40];  // 5 KB
  __shared__ unsigned short VtS[kHD * PST];   // 6.5 KB: [32][104]
  __shared__ float ksum[kHD];
  __shared__ float dinv_s[kCHUNK];
  int t = threadIdx.x;
  // ---- staging: q -> Pq cols 64..95, k -> kb ----
  {
    int i = t >> 2, j8 = (t & 3) * 8;
    const unsigned short* qrow = qkb + (size_t)(b * kG + g0 + i) * 512 + hh * kHD;
    *(ushort8*)&Pq[i * PST + 64 + j8] = *(const ushort8*)&qrow[j8];
    *(ushort8*)&kb[i * 40 + j8] = *(const ushort8*)&qrow[256 + j8];
  }
  // ---- staging: v -> VtS cols 0..63 (transposed, bf16) ----
#pragma unroll
  for (int r = 0; r < 2; r++) {
    int e = t + r * 256;
    int j = e >> 3, n0 = (e & 7) * 4;        // v row j, cols n0..n0+3
    float4 vv = *(const float4*)&vbuf[(size_t)(b * kG + g0 + j) * kD + hh * kHD + n0];
    VtS[(n0 + 0) * PST + j] = f2bf(vv.x);
    VtS[(n0 + 1) * PST + j] = f2bf(vv.y);
    VtS[(n0 + 2) * PST + j] = f2bf(vv.z);
    VtS[(n0 + 3) * PST + j] = f2bf(vv.w);
  }
  // ---- staging: S -> VtS cols 64..95 (transposed, bf16), ksum fp32 ----
  const float* sp = sums + (size_t)blk * kSUMSZ;
#pragma unroll
  for (int r = 0; r < 4; r++) {
    int e = t + r * 256;                     // S[m][n], m = e>>5, n = e&31
    VtS[(e & 31) * PST + 64 + (e >> 5)] = f2bf(sp[e]);
  }
  if (t < kHD) ksum[t] = sp[kHD * kHD + t];
  __syncthreads();

  const int w = t >> 6, lane = t & 63;
  const int lm = lane & 15, lq = lane >> 4;
  // ---- Stage 1: P via MFMA; wave w owns rows 16w..16w+15 ----
  {
    bf16x8 afr = __builtin_bit_cast(bf16x8,
        *reinterpret_cast<const ushort8*>(&Pq[(16 * w + lm) * PST + 64 + lq * 8]));
    floatx4 pacc[4];
#pragma unroll
    for (int jt = 0; jt < 4; jt++) {
      bf16x8 bfr = __builtin_bit_cast(bf16x8,
          *reinterpret_cast<const ushort8*>(&kb[(16 * jt + lm) * 40 + lq * 8]));
      pacc[jt] = __builtin_amdgcn_mfma_f32_16x16x32_bf16(
          afr, bfr, (floatx4){0.f, 0.f, 0.f, 0.f}, 0, 0, 0);
    }
    // write masked P̃ (bf16) to Pq cols 0..63; C-layout: col=lm', row=lq*4+r
#pragma unroll
    for (int jt = 0; jt < 4; jt++)
#pragma unroll
      for (int r = 0; r < 4; r++) {
        int row = 16 * w + lq * 4 + r, col = 16 * jt + lm;
        Pq[row * PST + col] = (col <= row) ? f2bf(pacc[jt][r]) : 0;
      }
    // den from fp32 accumulators + fp32 ksum
#pragma unroll
    for (int r = 0; r < 4; r++) {
      int row = 16 * w + lq * 4 + r;
      float ps = 0.f;
#pragma unroll
      for (int jt = 0; jt < 4; jt++) {
        int j = 16 * jt + lm;
        ps += (j <= row) ? pacc[jt][r] : 0.f;
      }
      ps += bf2f(Pq[row * PST + 64 + lm]) * ksum[lm];
      ps += bf2f(Pq[row * PST + 80 + lm]) * ksum[lm + 16];
      ps += __shfl_xor(ps, 1);
      ps += __shfl_xor(ps, 2);
      ps += __shfl_xor(ps, 4);
      ps += __shfl_xor(ps, 8);
      if (lm == 0) dinv_s[row] = 1.0f / (ps + 1e-16f);
    }
  }
  __syncthreads();

  // ---- Stage 2: O = [P̃|Q] · [V;S] (K=96), 6 MFMAs per wave ----
  {
    floatx4 oacc[2];
    oacc[0] = (floatx4){0.f, 0.f, 0.f, 0.f};
    oacc[1] = (floatx4){0.f, 0.f, 0.f, 0.f};
#pragma unroll
    for (int kc = 0; kc < 3; kc++) {
      bf16x8 af = __builtin_bit_cast(bf16x8,
          *reinterpret_cast<const ushort8*>(&Pq[(16 * w + lm) * PST + kc * 32 + lq * 8]));
#pragma unroll
      for (int jt = 0; jt < 2; jt++) {
        bf16x8 bfv = __builtin_bit_cast(bf16x8,
            *reinterpret_cast<const ushort8*>(&VtS[(16 * jt + lm) * PST + kc * 32 + lq * 8]));
        oacc[jt] = __builtin_amdgcn_mfma_f32_16x16x32_bf16(af, bfv, oacc[jt], 0, 0, 0);
      }
    }
    // epilogue: h += oacc * dinv  (C-layout: col=lm, row=lq*4+r)
#pragma unroll
    for (int jt = 0; jt < 2; jt++)
#pragma unroll
      for (int r = 0; r < 4; r++) {
        int row = 16 * w + lq * 4 + r, col = 16 * jt + lm;
        float* hp = h + (size_t)(b * kG + g0 + row) * kD + hh * kHD + col;
        *hp += oacc[jt][r] * dinv_s[row];
      }
  }
}

// ---------------------------------------------------------------------------
// out[row] = h[row,:] . Wo + bo. Wave-per-row, 4 rows/block.
__global__ __launch_bounds__(256) void final_kernel(
    const float* __restrict__ h, const float* __restrict__ Wo,
    const float* __restrict__ bo, float* __restrict__ out) {
  int w = threadIdx.x >> 6, lane = threadIdx.x & 63;
  size_t row = (size_t)blockIdx.x * 4 + w;
  float4 hv = *(const float4*)&h[row * kD + lane * 4];
  float4 wv = *(const float4*)&Wo[lane * 4];
  float s = hv.x * wv.x + hv.y * wv.y + hv.z * wv.z + hv.w * wv.w;
#pragma unroll
  for (int o = 32; o > 0; o >>= 1) s += __shfl_xor(s, o);
  if (lane == 0) out[row] = s + bo[0];
}

// ---------------------------------------------------------------------------
extern "C" void kernel_launch(void* const* d_in, const int* in_sizes, int n_in,
                              void* d_out, int out_size, void* d_ws, size_t ws_size,
                              hipStream_t stream) {
  const float* x    = (const float*)d_in[0];
  const float* ge   = (const float*)d_in[1];
  const float* Wq   = (const float*)d_in[2];
  const float* bq   = (const float*)d_in[3];
  const float* Wk   = (const float*)d_in[4];
  const float* bk   = (const float*)d_in[5];
  const float* Wv   = (const float*)d_in[6];
  const float* bv   = (const float*)d_in[7];
  const float* ln1g = (const float*)d_in[8];
  const float* ln1b = (const float*)d_in[9];
  const float* ln2g = (const float*)d_in[10];
  const float* ln2b = (const float*)d_in[11];
  const float* WU   = (const float*)d_in[12];
  const float* bU   = (const float*)d_in[13];
  const float* WV   = (const float*)d_in[14];
  const float* bV   = (const float*)d_in[15];
  const float* Wo   = (const float*)d_in[16];
  const float* bo   = (const float*)d_in[17];
  float* out = (float*)d_out;

  // Workspace layout (fp32 slot offsets; all 16B-aligned):
  float* ws = (float*)d_ws;
  float*          h       = ws;                        // [0, 2097152)
  unsigned short* zb      = (unsigned short*)(ws + 2097152);   // 2M bf16
  unsigned short* qkb     = (unsigned short*)(ws + 3145728);   // [8192][512] bf16
  float*          vbuf    = ws + 5242880;              // [8192][256] f32
  unsigned short* u       = (unsigned short*)(ws + 3145728);   // [8192][1024] bf16 (aliases qkb+vbuf)
  float*          sums    = ws + 9437184;              // 1,081,344 f32
  unsigned short* Wqkv_t  = (unsigned short*)(ws + 10518528);  // 786,432 bf16
  unsigned short* WU_t    = (unsigned short*)(ws + 10911744);  // 1,048,576 bf16
  unsigned short* WV_t    = (unsigned short*)(ws + 11436032);  // 1,048,576 bf16
  float*          bias_qkv= ws + 11960320;             // 3,072 f32

  dim3 blk256(256);
  convert_weights_kernel<<<kL * 704 + 12, blk256, 0, stream>>>(
      Wq, Wk, Wv, WU, WV, bq, bk, bv, Wqkv_t, WU_t, WV_t, bias_qkv);
  embed_kernel<<<kBG * kD / 256, blk256, 0, stream>>>(x, ge, h);
  for (int l = 0; l < kL; l++) {
    ln_kernel<<<kBG / 4, blk256, 0, stream>>>(h, ln1g + l * kD, ln1b + l * kD, zb);
    mfma_gemm<1><<<dim3(kQKVN / 64, kBG / 64), blk256, 0, stream>>>(
        zb, Wqkv_t + (size_t)l * kQKVN * kD, bias_qkv + l * kQKVN, qkb, vbuf,
        kBG, kQKVN, kD, kD);
    attn_sums_kernel<<<kB * kH * kNC, blk256, 0, stream>>>(qkb, vbuf, sums);
    attn_scan_kernel<<<kB * kH * 5, blk256, 0, stream>>>(sums);
    attn_out_kernel<<<kB * kH * kNC, blk256, 0, stream>>>(qkb, vbuf, sums, h);
    ln_kernel<<<kBG / 4, blk256, 0, stream>>>(h, ln2g + l * kD, ln2b + l * kD, zb);
    mfma_gemm<2><<<dim3(kFFN / 64, kBG / 64), blk256, 0, stream>>>(
        zb, WU_t + (size_t)l * kFFN * kD, bU + l * kFFN, u, nullptr,
        kBG, kFFN, kD, kD);
    // FFN2 split-K=2: h already holds the residual; each split atomicAdds.
    mfma_gemm<3><<<dim3(kD / 64, kBG / 64, 2), blk256, 0, stream>>>(
        u, WV_t + (size_t)l * kD * kFFN, bV + l * kD, h, nullptr,
        kBG, kD, kFFN, kFFN / 2);
  }
  final_kernel<<<kBG / 4, blk256, 0, stream>>>(h, Wo, bo, out);
}

// Round 15
// 357.653 us; speedup vs baseline: 1.0810x; 1.0810x over previous
//
#include <hip/hip_runtime.h>
#include <math.h>

// Problem constants
constexpr int kB = 4, kG = 2048, kD = 256, kH = 8, kHD = 32, kL = 4, kFFN = 1024;
constexpr int kBG = kB * kG;                  // 8192 tokens
constexpr int kCHUNK = 64;                    // linear-attn chunk length
constexpr int kNC = kG / kCHUNK;              // 32 chunks per sequence
constexpr int kSUMSZ = kHD * kHD + kHD;       // 1056 floats per chunk-state
constexpr int kQKVN = 3 * kD;                 // 768 fused QKV columns

typedef __bf16 bf16x8 __attribute__((ext_vector_type(8)));
typedef unsigned short ushort8 __attribute__((ext_vector_type(8)));
typedef float floatx4 __attribute__((ext_vector_type(4)));

__device__ __forceinline__ unsigned short f2bf(float f) {
  unsigned int u = __float_as_uint(f);
  u += 0x7fff + ((u >> 16) & 1);              // round-to-nearest-even
  return (unsigned short)(u >> 16);
}
__device__ __forceinline__ float bf2f(unsigned short u) {
  return __uint_as_float(((unsigned int)u) << 16);
}

__device__ __forceinline__ void load_lds_16(const void* g, void* l) {
  __builtin_amdgcn_global_load_lds((const __attribute__((address_space(1))) void*)g,
                                   (__attribute__((address_space(3))) void*)l,
                                   16, 0, 0);
}

// ---------------------------------------------------------------------------
// h[b,g,d] = gene_emb[g,d] + ree(x[b,g], d)
__global__ void embed_kernel(const float* __restrict__ x,
                             const float* __restrict__ ge,
                             float* __restrict__ h) {
  int idx = blockIdx.x * 256 + threadIdx.x;   // over kB*kG*kD = 2^21
  int d = idx & (kD - 1);
  int g = (idx >> 8) & (kG - 1);
  int b = idx >> 19;
  float xv = x[b * kG + g];
  int i = d & 127;
  float inv = expf(-(float)i * (4.6051701859880914f / 128.0f));  // 100^(-i/128)
  float f = xv * inv;
  float r = (d < 128) ? sinf(f) : cosf(f);
  if (xv == -10.0f) r = 0.0f;
  h[idx] = ge[g * kD + d] + r;
}

// ---------------------------------------------------------------------------
// Weight conversion: fp32 K-major -> bf16 N-major (transposed), plus QKV bias
// packing. One launch covers all layers.
__global__ void convert_weights_kernel(
    const float* __restrict__ Wq, const float* __restrict__ Wk,
    const float* __restrict__ Wv, const float* __restrict__ WU,
    const float* __restrict__ WV, const float* __restrict__ bq,
    const float* __restrict__ bk, const float* __restrict__ bv,
    unsigned short* __restrict__ Wqkv_t, unsigned short* __restrict__ WU_t,
    unsigned short* __restrict__ WV_t, float* __restrict__ bias_qkv) {
  int blk = blockIdx.x;
  if (blk >= kL * 704) {                       // bias-packing tail blocks
    int idx = (blk - kL * 704) * 256 + threadIdx.x;
    if (idx < kL * kQKVN) {
      int l = idx / kQKVN, n = idx % kQKVN;
      float v = (n < 256) ? bq[l * 256 + n]
              : (n < 512) ? bk[l * 256 + n - 256]
                          : bv[l * 256 + n - 512];
      bias_qkv[idx] = v;
    }
    return;
  }
  int l = blk / 704, id = blk % 704;
  const float* src;
  unsigned short* dst;
  int Ksrc, Nsrc, kt, nt;
  if (id < 192) {
    int m = id >> 6, tid = id & 63;
    src = (m == 0 ? Wq : m == 1 ? Wk : Wv) + (size_t)l * 256 * 256;
    dst = Wqkv_t + (size_t)l * kQKVN * 256 + (size_t)m * 256 * 256;
    Ksrc = 256; Nsrc = 256; kt = tid >> 3; nt = tid & 7;
  } else if (id < 448) {
    int tid = id - 192;
    src = WU + (size_t)l * 256 * 1024;
    dst = WU_t + (size_t)l * 1024 * 256;
    Ksrc = 256; Nsrc = 1024; kt = tid >> 5; nt = tid & 31;
  } else {
    int tid = id - 448;
    src = WV + (size_t)l * 1024 * 256;
    dst = WV_t + (size_t)l * 256 * 1024;
    Ksrc = 1024; Nsrc = 256; kt = tid >> 3; nt = tid & 7;
  }
  __shared__ float s[32][33];
  int tx = threadIdx.x & 31, ty = threadIdx.x >> 5;   // 32 x 8
#pragma unroll
  for (int r = 0; r < 4; r++)
    s[ty + r * 8][tx] = src[(size_t)(kt * 32 + ty + r * 8) * Nsrc + nt * 32 + tx];
  __syncthreads();
#pragma unroll
  for (int r = 0; r < 4; r++)
    dst[(size_t)(nt * 32 + ty + r * 8) * Ksrc + kt * 32 + tx] =
        f2bf(s[tx][ty + r * 8]);
}

// ---------------------------------------------------------------------------
// Row LayerNorm over D=256 -> bf16 output. Wave-per-row, 4 rows/block.
__global__ __launch_bounds__(256) void ln_kernel(
    const float* __restrict__ h, const float* __restrict__ gamma,
    const float* __restrict__ beta, unsigned short* __restrict__ z) {
  int w = threadIdx.x >> 6, lane = threadIdx.x & 63;
  size_t row = (size_t)blockIdx.x * 4 + w;
  float4 v = *(const float4*)&h[row * kD + lane * 4];
  float s = v.x + v.y + v.z + v.w;
  float sq = v.x * v.x + v.y * v.y + v.z * v.z + v.w * v.w;
#pragma unroll
  for (int o = 32; o > 0; o >>= 1) {
    s += __shfl_xor(s, o);
    sq += __shfl_xor(sq, o);
  }
  float mu = s * (1.0f / kD);
  float var = sq * (1.0f / kD) - mu * mu;
  float r = rsqrtf(var + 1e-5f);
  float4 g4 = *(const float4*)&gamma[lane * 4];
  float4 b4 = *(const float4*)&beta[lane * 4];
  float y0 = (v.x - mu) * r * g4.x + b4.x;
  float y1 = (v.y - mu) * r * g4.y + b4.y;
  float y2 = (v.z - mu) * r * g4.z + b4.z;
  float y3 = (v.w - mu) * r * g4.w + b4.w;
  unsigned int u0 = (unsigned int)f2bf(y0) | ((unsigned int)f2bf(y1) << 16);
  unsigned int u1 = (unsigned int)f2bf(y2) | ((unsigned int)f2bf(y3) << 16);
  uint2 uu; uu.x = u0; uu.y = u1;
  *(uint2*)&z[row * kD + lane * 4] = uu;
}

// ---------------------------------------------------------------------------
// bf16 MFMA GEMM, 64x64 tile, BK=64 double-buffered (2 k-chunks per barrier:
// 8 MFMAs/wave between barriers; 32 KB LDS, big grids -> 5+ blocks/CU).
// Best measured shape (r9/r11); BM=128 (r10), full K-unroll (r13) and
// split-K (r14) all regressed — block count beats per-wave density here.
// A: M x K bf16 (row-major), Bt: N x K bf16 (row-major = W transposed).
// EPI: 1 = fused QKV: cols<512 -> square -> bf16 into Cout [M][512];
//                     cols>=512 -> fp32 into Cout2 [M][256]
//      2 = exact gelu, bf16 out
//      3 = residual add (Cres == C), fp32 out
template <int EPI>
__global__ __launch_bounds__(256) void mfma_gemm(
    const unsigned short* __restrict__ A, const unsigned short* __restrict__ Bt,
    const float* __restrict__ bias, void* __restrict__ Cout,
    void* __restrict__ Cout2, const float* __restrict__ Cres,
    int M, int N, int K) {
  __shared__ unsigned short As[2][2][64 * 32];   // [buf][kc] = 16 KB
  __shared__ unsigned short Bs[2][2][64 * 32];   // 16 KB
  const int t = threadIdx.x;
  const int w = t >> 6, lane = t & 63;
  const int bm = blockIdx.y * 64, bn = blockIdx.x * 64;
  const int wm = (w >> 1) * 32, wn = (w & 1) * 32;

  const int srow = lane >> 2;            // 0..15 within chunk
  const int skof = (lane & 3) * 8;       // k element offset of 16B piece
  const unsigned short* ap = A + (size_t)(bm + w * 16 + srow) * K + skof;
  const unsigned short* bp = Bt + (size_t)(bn + w * 16 + srow) * K + skof;

  floatx4 acc[2][2];
#pragma unroll
  for (int i = 0; i < 2; i++)
#pragma unroll
    for (int j = 0; j < 2; j++) acc[i][j] = (floatx4){0.f, 0.f, 0.f, 0.f};

  const int lm = lane & 15, lq = lane >> 4;
  const int nsteps = K >> 6;             // K is a multiple of 64

  // Prologue: stage step 0 (two 32-deep chunks) into buffer 0.
  load_lds_16(ap, &As[0][0][w * 512]);
  load_lds_16(ap + 32, &As[0][1][w * 512]);
  load_lds_16(bp, &Bs[0][0][w * 512]);
  load_lds_16(bp + 32, &Bs[0][1][w * 512]);
  __syncthreads();

  for (int s = 0; s < nsteps; s++) {
    const int cur = s & 1, nxt = cur ^ 1;
    if (s + 1 < nsteps) {                     // prefetch next 64-deep step
      const int k1 = (s + 1) * 64;
      load_lds_16(ap + k1, &As[nxt][0][w * 512]);
      load_lds_16(ap + k1 + 32, &As[nxt][1][w * 512]);
      load_lds_16(bp + k1, &Bs[nxt][0][w * 512]);
      load_lds_16(bp + k1 + 32, &Bs[nxt][1][w * 512]);
    }
#pragma unroll
    for (int kc = 0; kc < 2; kc++) {
      const unsigned short* afp = &As[cur][kc][(wm + lm) * 32 + lq * 8];
      const unsigned short* bfp = &Bs[cur][kc][(wn + lm) * 32 + lq * 8];
      bf16x8 af[2], bfr[2];
#pragma unroll
      for (int i = 0; i < 2; i++)
        af[i] = __builtin_bit_cast(bf16x8,
            *reinterpret_cast<const ushort8*>(afp + i * 16 * 32));
#pragma unroll
      for (int j = 0; j < 2; j++)
        bfr[j] = __builtin_bit_cast(bf16x8,
            *reinterpret_cast<const ushort8*>(bfp + j * 16 * 32));
#pragma unroll
      for (int i = 0; i < 2; i++)
#pragma unroll
        for (int j = 0; j < 2; j++)
          acc[i][j] = __builtin_amdgcn_mfma_f32_16x16x32_bf16(af[i], bfr[j],
                                                              acc[i][j], 0, 0, 0);
    }
    __syncthreads();
  }

  const int r0 = bm + wm + lq * 4;
  const int c0 = bn + wn + lm;
#pragma unroll
  for (int j = 0; j < 2; j++) {
    int col = c0 + j * 16;
    float bv = bias[col];
#pragma unroll
    for (int i = 0; i < 2; i++) {
      int rowb = r0 + i * 16;
#pragma unroll
      for (int r = 0; r < 4; r++) {
        int row = rowb + r;
        float v = acc[i][j][r] + bv;
        if (EPI == 1) {
          if (col < 512) {                    // q,k: squared, bf16
            ((unsigned short*)Cout)[(size_t)row * 512 + col] = f2bf(v * v);
          } else {                            // v: fp32
            ((float*)Cout2)[(size_t)row * 256 + col - 512] = v;
          }
        } else if (EPI == 2) {
          float g = 0.5f * v * (1.0f + erff(v * 0.70710678118654752f));
          ((unsigned short*)Cout)[(size_t)row * N + col] = f2bf(g);
        } else {
          size_t idx = (size_t)row * N + col;
          ((float*)Cout)[idx] = Cres[idx] + v;
        }
      }
    }
  }
}

// ---------------------------------------------------------------------------
// Per-chunk summaries via MFMA: Skv = k̃ᵀ·ṽ (K=64). k,v staged transposed;
// 4 waves x one 16x16 tile x 2 MFMAs. ksum fp32 from kT rows.
__global__ __launch_bounds__(256) void attn_sums_kernel(
    const unsigned short* __restrict__ qkb, const float* __restrict__ vbuf,
    float* __restrict__ sums) {
  int blk = blockIdx.x;              // b*(H*NC) + h*NC + c
  int c = blk & (kNC - 1);
  int hh = (blk >> 5) & (kH - 1);
  int b = blk >> 8;
  int g0 = c * kCHUNK;
  constexpr int TST = 72;                    // transposed row stride (bf16)
  __shared__ unsigned short kT[kHD * TST];   // [m][g] 4.5 KB
  __shared__ unsigned short vT[kHD * TST];   // [n][g] 4.5 KB
  int t = threadIdx.x;
  // k (bf16, already squared): transpose into kT
  {
    int i = t >> 2, j8 = (t & 3) * 8;        // row g0+i, k-feature cols j8..+7
    ushort8 kv = *(const ushort8*)&qkb[(size_t)(b * kG + g0 + i) * 512 + 256 +
                                       hh * kHD + j8];
#pragma unroll
    for (int e = 0; e < 8; e++) kT[(j8 + e) * TST + i] = kv[e];
  }
  // v (fp32): bf16 transpose into vT
#pragma unroll
  for (int r = 0; r < 2; r++) {
    int e = t + r * 256;
    int j = e >> 3, n0 = (e & 7) * 4;
    float4 vv = *(const float4*)&vbuf[(size_t)(b * kG + g0 + j) * kD + hh * kHD + n0];
    vT[(n0 + 0) * TST + j] = f2bf(vv.x);
    vT[(n0 + 1) * TST + j] = f2bf(vv.y);
    vT[(n0 + 2) * TST + j] = f2bf(vv.z);
    vT[(n0 + 3) * TST + j] = f2bf(vv.w);
  }
  __syncthreads();
  float* outp = sums + (size_t)blk * kSUMSZ;
  const int w = t >> 6, lane = t & 63;
  const int lm = lane & 15, lq = lane >> 4;
  const int m0 = (w >> 1) * 16, n0 = (w & 1) * 16;
  floatx4 acc = (floatx4){0.f, 0.f, 0.f, 0.f};
#pragma unroll
  for (int kc = 0; kc < 2; kc++) {
    bf16x8 af = __builtin_bit_cast(bf16x8,
        *reinterpret_cast<const ushort8*>(&kT[(m0 + lm) * TST + kc * 32 + lq * 8]));
    bf16x8 bf = __builtin_bit_cast(bf16x8,
        *reinterpret_cast<const ushort8*>(&vT[(n0 + lm) * TST + kc * 32 + lq * 8]));
    acc = __builtin_amdgcn_mfma_f32_16x16x32_bf16(af, bf, acc, 0, 0, 0);
  }
  // C-layout: row (m) = m0 + lq*4 + r, col (n) = n0 + lm
#pragma unroll
  for (int r = 0; r < 4; r++)
    outp[(m0 + lq * 4 + r) * kHD + n0 + lm] = acc[r];
  // ksum[m] = sum_g k[g][m] — fp32 accumulate from kT row m
  if (t < kHD) {
    float s = 0;
#pragma unroll
    for (int g = 0; g < kCHUNK; g++) s += bf2f(kT[t * TST + g]);
    outp[kHD * kHD + t] = s;
  }
}

// ---------------------------------------------------------------------------
// Exclusive prefix scan over chunks. grid = kB*kH*5, block = 256.
// (Separate launch on purpose: in-kernel fusion needs per-block device-scope
// fences, which cost a per-block L2 writeback on multi-XCD CDNA — r12.)
__global__ void attn_scan_kernel(float* __restrict__ sums) {
  int bh = blockIdx.x / 5, part = blockIdx.x % 5;
  int e = part * 256 + threadIdx.x;
  if (e >= kSUMSZ) return;
  float* base = sums + (size_t)bh * kNC * kSUMSZ + e;
  float v[kNC];
#pragma unroll
  for (int c = 0; c < kNC; c++) v[c] = base[(size_t)c * kSUMSZ];
  float run = 0;
#pragma unroll
  for (int c = 0; c < kNC; c++) {
    float tv = v[c];
    base[(size_t)c * kSUMSZ] = run;
    run += tv;
  }
}

// ---------------------------------------------------------------------------
// Per-chunk output, both stages on MFMA (round-9 structure).
__global__ __launch_bounds__(256) void attn_out_kernel(
    const unsigned short* __restrict__ qkb, const float* __restrict__ vbuf,
    const float* __restrict__ sums, float* __restrict__ h) {
  int blk = blockIdx.x;
  int c = blk & (kNC - 1);
  int hh = (blk >> 5) & (kH - 1);
  int b = blk >> 8;
  int g0 = c * kCHUNK;
  constexpr int PST = 104;                    // row stride (bf16 elems)
  __shared__ unsigned short Pq[kCHUNK * PST]; // 13 KB: [64][104]
  __shared__ unsigned short kb[kCHUNK * 40];  // 5 KB
  __shared__ unsigned short VtS[kHD * PST];   // 6.5 KB: [32][104]
  __shared__ float ksum[kHD];
  __shared__ float dinv_s[kCHUNK];
  int t = threadIdx.x;
  // ---- staging: q -> Pq cols 64..95, k -> kb ----
  {
    int i = t >> 2, j8 = (t & 3) * 8;
    const unsigned short* qrow = qkb + (size_t)(b * kG + g0 + i) * 512 + hh * kHD;
    *(ushort8*)&Pq[i * PST + 64 + j8] = *(const ushort8*)&qrow[j8];
    *(ushort8*)&kb[i * 40 + j8] = *(const ushort8*)&qrow[256 + j8];
  }
  // ---- staging: v -> VtS cols 0..63 (transposed, bf16) ----
#pragma unroll
  for (int r = 0; r < 2; r++) {
    int e = t + r * 256;
    int j = e >> 3, n0 = (e & 7) * 4;        // v row j, cols n0..n0+3
    float4 vv = *(const float4*)&vbuf[(size_t)(b * kG + g0 + j) * kD + hh * kHD + n0];
    VtS[(n0 + 0) * PST + j] = f2bf(vv.x);
    VtS[(n0 + 1) * PST + j] = f2bf(vv.y);
    VtS[(n0 + 2) * PST + j] = f2bf(vv.z);
    VtS[(n0 + 3) * PST + j] = f2bf(vv.w);
  }
  // ---- staging: S -> VtS cols 64..95 (transposed, bf16), ksum fp32 ----
  const float* sp = sums + (size_t)blk * kSUMSZ;
#pragma unroll
  for (int r = 0; r < 4; r++) {
    int e = t + r * 256;                     // S[m][n], m = e>>5, n = e&31
    VtS[(e & 31) * PST + 64 + (e >> 5)] = f2bf(sp[e]);
  }
  if (t < kHD) ksum[t] = sp[kHD * kHD + t];
  __syncthreads();

  const int w = t >> 6, lane = t & 63;
  const int lm = lane & 15, lq = lane >> 4;
  // ---- Stage 1: P via MFMA; wave w owns rows 16w..16w+15 ----
  {
    bf16x8 afr = __builtin_bit_cast(bf16x8,
        *reinterpret_cast<const ushort8*>(&Pq[(16 * w + lm) * PST + 64 + lq * 8]));
    floatx4 pacc[4];
#pragma unroll
    for (int jt = 0; jt < 4; jt++) {
      bf16x8 bfr = __builtin_bit_cast(bf16x8,
          *reinterpret_cast<const ushort8*>(&kb[(16 * jt + lm) * 40 + lq * 8]));
      pacc[jt] = __builtin_amdgcn_mfma_f32_16x16x32_bf16(
          afr, bfr, (floatx4){0.f, 0.f, 0.f, 0.f}, 0, 0, 0);
    }
    // write masked P̃ (bf16) to Pq cols 0..63; C-layout: col=lm', row=lq*4+r
#pragma unroll
    for (int jt = 0; jt < 4; jt++)
#pragma unroll
      for (int r = 0; r < 4; r++) {
        int row = 16 * w + lq * 4 + r, col = 16 * jt + lm;
        Pq[row * PST + col] = (col <= row) ? f2bf(pacc[jt][r]) : 0;
      }
    // den from fp32 accumulators + fp32 ksum
#pragma unroll
    for (int r = 0; r < 4; r++) {
      int row = 16 * w + lq * 4 + r;
      float ps = 0.f;
#pragma unroll
      for (int jt = 0; jt < 4; jt++) {
        int j = 16 * jt + lm;
        ps += (j <= row) ? pacc[jt][r] : 0.f;
      }
      ps += bf2f(Pq[row * PST + 64 + lm]) * ksum[lm];
      ps += bf2f(Pq[row * PST + 80 + lm]) * ksum[lm + 16];
      ps += __shfl_xor(ps, 1);
      ps += __shfl_xor(ps, 2);
      ps += __shfl_xor(ps, 4);
      ps += __shfl_xor(ps, 8);
      if (lm == 0) dinv_s[row] = 1.0f / (ps + 1e-16f);
    }
  }
  __syncthreads();

  // ---- Stage 2: O = [P̃|Q] · [V;S] (K=96), 6 MFMAs per wave ----
  {
    floatx4 oacc[2];
    oacc[0] = (floatx4){0.f, 0.f, 0.f, 0.f};
    oacc[1] = (floatx4){0.f, 0.f, 0.f, 0.f};
#pragma unroll
    for (int kc = 0; kc < 3; kc++) {
      bf16x8 af = __builtin_bit_cast(bf16x8,
          *reinterpret_cast<const ushort8*>(&Pq[(16 * w + lm) * PST + kc * 32 + lq * 8]));
#pragma unroll
      for (int jt = 0; jt < 2; jt++) {
        bf16x8 bfv = __builtin_bit_cast(bf16x8,
            *reinterpret_cast<const ushort8*>(&VtS[(16 * jt + lm) * PST + kc * 32 + lq * 8]));
        oacc[jt] = __builtin_amdgcn_mfma_f32_16x16x32_bf16(af, bfv, oacc[jt], 0, 0, 0);
      }
    }
    // epilogue: h += oacc * dinv  (C-layout: col=lm, row=lq*4+r)
#pragma unroll
    for (int jt = 0; jt < 2; jt++)
#pragma unroll
      for (int r = 0; r < 4; r++) {
        int row = 16 * w + lq * 4 + r, col = 16 * jt + lm;
        float* hp = h + (size_t)(b * kG + g0 + row) * kD + hh * kHD + col;
        *hp += oacc[jt][r] * dinv_s[row];
      }
  }
}

// ---------------------------------------------------------------------------
// out[row] = h[row,:] . Wo + bo. Wave-per-row, 4 rows/block.
__global__ __launch_bounds__(256) void final_kernel(
    const float* __restrict__ h, const float* __restrict__ Wo,
    const float* __restrict__ bo, float* __restrict__ out) {
  int w = threadIdx.x >> 6, lane = threadIdx.x & 63;
  size_t row = (size_t)blockIdx.x * 4 + w;
  float4 hv = *(const float4*)&h[row * kD + lane * 4];
  float4 wv = *(const float4*)&Wo[lane * 4];
  float s = hv.x * wv.x + hv.y * wv.y + hv.z * wv.z + hv.w * wv.w;
#pragma unroll
  for (int o = 32; o > 0; o >>= 1) s += __shfl_xor(s, o);
  if (lane == 0) out[row] = s + bo[0];
}

// ---------------------------------------------------------------------------
extern "C" void kernel_launch(void* const* d_in, const int* in_sizes, int n_in,
                              void* d_out, int out_size, void* d_ws, size_t ws_size,
                              hipStream_t stream) {
  const float* x    = (const float*)d_in[0];
  const float* ge   = (const float*)d_in[1];
  const float* Wq   = (const float*)d_in[2];
  const float* bq   = (const float*)d_in[3];
  const float* Wk   = (const float*)d_in[4];
  const float* bk   = (const float*)d_in[5];
  const float* Wv   = (const float*)d_in[6];
  const float* bv   = (const float*)d_in[7];
  const float* ln1g = (const float*)d_in[8];
  const float* ln1b = (const float*)d_in[9];
  const float* ln2g = (const float*)d_in[10];
  const float* ln2b = (const float*)d_in[11];
  const float* WU   = (const float*)d_in[12];
  const float* bU   = (const float*)d_in[13];
  const float* WV   = (const float*)d_in[14];
  const float* bV   = (const float*)d_in[15];
  const float* Wo   = (const float*)d_in[16];
  const float* bo   = (const float*)d_in[17];
  float* out = (float*)d_out;

  // Workspace layout (fp32 slot offsets; all 16B-aligned):
  float* ws = (float*)d_ws;
  float*          h       = ws;                        // [0, 2097152)
  unsigned short* zb      = (unsigned short*)(ws + 2097152);   // 2M bf16
  unsigned short* qkb     = (unsigned short*)(ws + 3145728);   // [8192][512] bf16
  float*          vbuf    = ws + 5242880;              // [8192][256] f32
  unsigned short* u       = (unsigned short*)(ws + 3145728);   // [8192][1024] bf16 (aliases qkb+vbuf)
  float*          sums    = ws + 9437184;              // 1,081,344 f32
  unsigned short* Wqkv_t  = (unsigned short*)(ws + 10518528);  // 786,432 bf16
  unsigned short* WU_t    = (unsigned short*)(ws + 10911744);  // 1,048,576 bf16
  unsigned short* WV_t    = (unsigned short*)(ws + 11436032);  // 1,048,576 bf16
  float*          bias_qkv= ws + 11960320;             // 3,072 f32

  dim3 blk256(256);
  convert_weights_kernel<<<kL * 704 + 12, blk256, 0, stream>>>(
      Wq, Wk, Wv, WU, WV, bq, bk, bv, Wqkv_t, WU_t, WV_t, bias_qkv);
  embed_kernel<<<kBG * kD / 256, blk256, 0, stream>>>(x, ge, h);
  for (int l = 0; l < kL; l++) {
    ln_kernel<<<kBG / 4, blk256, 0, stream>>>(h, ln1g + l * kD, ln1b + l * kD, zb);
    mfma_gemm<1><<<dim3(kQKVN / 64, kBG / 64), blk256, 0, stream>>>(
        zb, Wqkv_t + (size_t)l * kQKVN * kD, bias_qkv + l * kQKVN, qkb, vbuf,
        nullptr, kBG, kQKVN, kD);
    attn_sums_kernel<<<kB * kH * kNC, blk256, 0, stream>>>(qkb, vbuf, sums);
    attn_scan_kernel<<<kB * kH * 5, blk256, 0, stream>>>(sums);
    attn_out_kernel<<<kB * kH * kNC, blk256, 0, stream>>>(qkb, vbuf, sums, h);
    ln_kernel<<<kBG / 4, blk256, 0, stream>>>(h, ln2g + l * kD, ln2b + l * kD, zb);
    mfma_gemm<2><<<dim3(kFFN / 64, kBG / 64), blk256, 0, stream>>>(
        zb, WU_t + (size_t)l * kFFN * kD, bU + l * kFFN, u, nullptr, nullptr,
        kBG, kFFN, kD);
    mfma_gemm<3><<<dim3(kD / 64, kBG / 64), blk256, 0, stream>>>(
        u, WV_t + (size_t)l * kD * kFFN, bV + l * kD, h, nullptr, h,
        kBG, kD, kFFN);
  }
  final_kernel<<<kBG / 4, blk256, 0, stream>>>(h, Wo, bo, out);
}